// Round 1
// baseline (5116.001 us; speedup 1.0000x reference)
//
#include <hip/hip_runtime.h>

#define TSTEPS 1000
#define KBINS  10
#define SBIN   100
#define BETA   0.9f
#define THR    1.0f
#define CDIV(a,b) (((a)+(b)-1)/(b))

// ---------------------------------------------------------------------------
// Layer 1 fused: conv(x, w1, stride2, SAME pad_lo=(0,0)) + membrane scan +
// per-bin mean/std stats + uint8 spike output.  One thread per layer-1 pixel.
// x: [1000,1,100,368], out spk1: [1000,4,50,184] u8, skip0: [80,50,184]
// ---------------------------------------------------------------------------
__global__ void k_l1_fused(const float* __restrict__ x,
                           const float* __restrict__ w1,
                           const float* __restrict__ b1,
                           unsigned char* __restrict__ spk1,
                           float* __restrict__ skip0) {
    const int HW  = 9200;    // 50*184
    const int CHW = 36800;   // 4*HW
    int p = blockIdx.x * blockDim.x + threadIdx.x;
    if (p >= CHW) return;
    int c  = p / HW;
    int hw = p - c * HW;
    int h  = hw / 184;
    int w  = hw - h * 184;

    int r0 = 2 * h, c0 = 2 * w;
    float wt[9];
    int   xoff[9];
    #pragma unroll
    for (int kh = 0; kh < 3; kh++) {
        int r = r0 + kh;
        bool rok = (r < 100);
        int rc = rok ? r : 99;
        #pragma unroll
        for (int kw = 0; kw < 3; kw++) {
            int cc = c0 + kw;
            bool cok = (cc < 368);
            int ccc = cok ? cc : 367;
            int j = kh * 3 + kw;
            wt[j]   = (rok && cok) ? w1[c * 9 + j] : 0.0f;  // zero-weight OOB taps
            xoff[j] = rc * 368 + ccc;                       // clamped (safe) index
        }
    }
    float bias = b1[c];

    float m = 0.0f;
    for (int k = 0; k < KBINS; k++) {
        float s = 0.0f, q = 0.0f;
        for (int i = 0; i < SBIN; i++) {
            int t = k * SBIN + i;
            const float* xt = x + (size_t)t * 36800;
            float acc = bias;
            #pragma unroll
            for (int j = 0; j < 9; j++)
                acc = fmaf(xt[xoff[j]], wt[j], acc);
            m = BETA * m + acc;
            float sp = (m - THR > 0.0f) ? 1.0f : 0.0f;
            m -= sp * THR;                      // soft reset
            spk1[(size_t)t * CHW + p] = (unsigned char)sp;
            s += m;                             // stats on post-reset membrane
            q = fmaf(m, m, q);
        }
        float mean = s * (1.0f / SBIN);
        float var  = q * (1.0f / SBIN) - mean * mean;
        float sd   = sqrtf(fmaxf(var, 1e-8f));
        // skip channel = k*2C + {0:mean, C:std} + c  (C=4)
        skip0[(size_t)(k * 8 + c) * HW + hw]     = mean;
        skip0[(size_t)(k * 8 + 4 + c) * HW + hw] = sd;
    }
}

// ---------------------------------------------------------------------------
// Stride-2 3x3 conv over all timesteps, uint8 spike input -> fp32 output.
// One thread per output element (t, co, h, w).
// ---------------------------------------------------------------------------
__global__ void k_conv_s2(const unsigned char* __restrict__ spk_in,
                          const float* __restrict__ wt,
                          const float* __restrict__ bias,
                          float* __restrict__ out,
                          int Cin, int Hin, int Win,
                          int Cout, int Hout, int Wout,
                          int padh, int padw, int total) {
    int n = blockIdx.x * blockDim.x + threadIdx.x;
    if (n >= total) return;
    int w   = n % Wout;
    int tmp = n / Wout;
    int h   = tmp % Hout;
    tmp    /= Hout;
    int co  = tmp % Cout;
    int t   = tmp / Cout;

    // Precompute tap offsets + validity masks (thread-invariant over ci)
    int   off[9];
    float msk[9];
    #pragma unroll
    for (int kh = 0; kh < 3; kh++) {
        int r = 2 * h + kh - padh;
        bool rok = (r >= 0) && (r < Hin);
        int rc = rok ? r : 0;
        #pragma unroll
        for (int kw = 0; kw < 3; kw++) {
            int cc = 2 * w + kw - padw;
            bool cok = (cc >= 0) && (cc < Win);
            int ccc = cok ? cc : 0;
            int j = kh * 3 + kw;
            off[j] = rc * Win + ccc;
            msk[j] = (rok && cok) ? 1.0f : 0.0f;
        }
    }

    const unsigned char* in_t = spk_in + (size_t)t * Cin * Hin * Win;
    const float* wco = wt + (size_t)co * Cin * 9;
    float acc = bias[co];
    for (int ci = 0; ci < Cin; ci++) {
        const unsigned char* ic = in_t + (size_t)ci * Hin * Win;
        const float* wci = wco + ci * 9;
        #pragma unroll
        for (int j = 0; j < 9; j++) {
            float v = msk[j] * (float)ic[off[j]];
            acc = fmaf(v, wci[j], acc);
        }
    }
    out[n] = acc;
}

// ---------------------------------------------------------------------------
// Membrane scan for layers 2-4: one thread per pixel, loops t=0..999.
// Reads conv output cbuf [1000, C*HW], writes uint8 spikes (optional) and
// per-bin mean/std into skip buffer [K*2*C, HW].
// ---------------------------------------------------------------------------
__global__ void k_scan(const float* __restrict__ cbuf,
                       unsigned char* __restrict__ spk_out,
                       float* __restrict__ skip,
                       int C, int HW, int write_spk) {
    int CHW = C * HW;
    int p = blockIdx.x * blockDim.x + threadIdx.x;
    if (p >= CHW) return;
    int c  = p / HW;
    int hw = p - c * HW;

    float m = 0.0f;
    for (int k = 0; k < KBINS; k++) {
        float s = 0.0f, q = 0.0f;
        #pragma unroll 4
        for (int i = 0; i < SBIN; i++) {
            int t = k * SBIN + i;
            float v = cbuf[(size_t)t * CHW + p];
            m = BETA * m + v;
            float sp = (m - THR > 0.0f) ? 1.0f : 0.0f;
            m -= sp * THR;
            if (write_spk) spk_out[(size_t)t * CHW + p] = (unsigned char)sp;
            s += m;
            q = fmaf(m, m, q);
        }
        float mean = s * (1.0f / SBIN);
        float var  = q * (1.0f / SBIN) - mean * mean;
        float sd   = sqrtf(fmaxf(var, 1e-8f));
        skip[(size_t)(k * 2 * C + c) * HW + hw]     = mean;
        skip[(size_t)(k * 2 * C + C + c) * HW + hw] = sd;
    }
}

// ---------------------------------------------------------------------------
// Decoder: 3x3 stride-1 SAME conv + ReLU. One thread per output element.
// ---------------------------------------------------------------------------
__global__ void k_conv3x3_relu(const float* __restrict__ in, int Cin, int H, int W,
                               const float* __restrict__ wt,
                               const float* __restrict__ bias,
                               float* __restrict__ out, int Cout) {
    int total = Cout * H * W;
    int n = blockIdx.x * blockDim.x + threadIdx.x;
    if (n >= total) return;
    int w   = n % W;
    int tmp = n / W;
    int h   = tmp % H;
    int co  = tmp / H;

    float acc = bias[co];
    const float* wco = wt + (size_t)co * Cin * 9;
    for (int ci = 0; ci < Cin; ci++) {
        const float* ic  = in + (size_t)ci * H * W;
        const float* wci = wco + ci * 9;
        #pragma unroll
        for (int kh = 0; kh < 3; kh++) {
            int r = h + kh - 1;
            if ((unsigned)r >= (unsigned)H) continue;
            #pragma unroll
            for (int kw = 0; kw < 3; kw++) {
                int cc = w + kw - 1;
                if ((unsigned)cc >= (unsigned)W) continue;
                acc = fmaf(ic[r * W + cc], wci[kh * 3 + kw], acc);
            }
        }
    }
    out[n] = fmaxf(acc, 0.0f);
}

// ---------------------------------------------------------------------------
// Bilinear upsample (JAX half-pixel, edge-clamp) of up_src into channels
// [0,Cup), copy skip into channels [Cup, Cup+Cskip).  Output [Cup+Cskip,Ho,Wo].
// ---------------------------------------------------------------------------
__global__ void k_up_cat(const float* __restrict__ up_src, int Cup, int Hi, int Wi,
                         const float* __restrict__ skip, int Cskip,
                         float* __restrict__ out, int Ho, int Wo) {
    int total = (Cup + Cskip) * Ho * Wo;
    int n = blockIdx.x * blockDim.x + threadIdx.x;
    if (n >= total) return;
    int w   = n % Wo;
    int tmp = n / Wo;
    int h   = tmp % Ho;
    int c   = tmp / Ho;
    float v;
    if (c < Cup) {
        float ph = (h + 0.5f) * (float)Hi / (float)Ho - 0.5f;
        float pw = (w + 0.5f) * (float)Wi / (float)Wo - 0.5f;
        float fh = floorf(ph), fw = floorf(pw);
        int h0 = (int)fh, w0 = (int)fw;
        float ah = ph - fh, aw = pw - fw;
        int h0c = min(max(h0, 0), Hi - 1), h1c = min(max(h0 + 1, 0), Hi - 1);
        int w0c = min(max(w0, 0), Wi - 1), w1c = min(max(w0 + 1, 0), Wi - 1);
        const float* sc = up_src + (size_t)c * Hi * Wi;
        float v00 = sc[h0c * Wi + w0c], v01 = sc[h0c * Wi + w1c];
        float v10 = sc[h1c * Wi + w0c], v11 = sc[h1c * Wi + w1c];
        v = (1.0f - ah) * ((1.0f - aw) * v00 + aw * v01)
          + ah * ((1.0f - aw) * v10 + aw * v11);
    } else {
        v = skip[(size_t)(c - Cup) * Ho * Wo + h * Wo + w];
    }
    out[n] = v;
}

// ---------------------------------------------------------------------------
// Final: bilinear up d1 [8,50,184] -> (100,368), fused 1x1 conv -> out.
// ---------------------------------------------------------------------------
__global__ void k_final(const float* __restrict__ d1,
                        const float* __restrict__ wo,
                        const float* __restrict__ bo,
                        float* __restrict__ out) {
    int n = blockIdx.x * blockDim.x + threadIdx.x;
    if (n >= 36800) return;
    int w = n % 368, h = n / 368;
    float ph = (h + 0.5f) * 0.5f - 0.5f;
    float pw = (w + 0.5f) * 0.5f - 0.5f;
    float fh = floorf(ph), fw = floorf(pw);
    int h0 = (int)fh, w0 = (int)fw;
    float ah = ph - fh, aw = pw - fw;
    int h0c = min(max(h0, 0), 49),  h1c = min(max(h0 + 1, 0), 49);
    int w0c = min(max(w0, 0), 183), w1c = min(max(w0 + 1, 0), 183);
    float acc = bo[0];
    #pragma unroll
    for (int c = 0; c < 8; c++) {
        const float* sc = d1 + c * 9200;
        float v00 = sc[h0c * 184 + w0c], v01 = sc[h0c * 184 + w1c];
        float v10 = sc[h1c * 184 + w0c], v11 = sc[h1c * 184 + w1c];
        float v = (1.0f - ah) * ((1.0f - aw) * v00 + aw * v01)
                + ah * ((1.0f - aw) * v10 + aw * v11);
        acc = fmaf(wo[c], v, acc);
    }
    out[n] = acc;
}

// ---------------------------------------------------------------------------
extern "C" void kernel_launch(void* const* d_in, const int* in_sizes, int n_in,
                              void* d_out, int out_size, void* d_ws, size_t ws_size,
                              hipStream_t stream) {
    (void)in_sizes; (void)n_in; (void)out_size; (void)ws_size;
    const float* x   = (const float*)d_in[0];
    const float* w1  = (const float*)d_in[1];
    const float* b1  = (const float*)d_in[2];
    const float* w2  = (const float*)d_in[3];
    const float* b2  = (const float*)d_in[4];
    const float* w3  = (const float*)d_in[5];
    const float* b3  = (const float*)d_in[6];
    const float* w4  = (const float*)d_in[7];
    const float* b4  = (const float*)d_in[8];
    const float* dw4 = (const float*)d_in[9];
    const float* db4 = (const float*)d_in[10];
    const float* dw3 = (const float*)d_in[11];
    const float* db3 = (const float*)d_in[12];
    const float* dw2 = (const float*)d_in[13];
    const float* db2 = (const float*)d_in[14];
    const float* dw1 = (const float*)d_in[15];
    const float* db1 = (const float*)d_in[16];
    const float* wo  = (const float*)d_in[17];
    const float* bo  = (const float*)d_in[18];
    float* out = (float*)d_out;

    // Workspace carve-up (~151 MB total)
    char* ws = (char*)d_ws;
    size_t off = 0;
    auto alloc = [&](size_t bytes) -> void* {
        void* p = ws + off;
        off += (bytes + 255) & ~(size_t)255;
        return p;
    };
    unsigned char* spk1 = (unsigned char*)alloc(36800000);   // [1000,4,50,184]
    unsigned char* spk2 = (unsigned char*)alloc(18400000);   // [1000,8,25,92]
    unsigned char* spk3 = (unsigned char*)alloc(9568000);    // [1000,16,13,46]
    float* cbuf  = (float*)alloc(73600000);                  // reused c2/c3/c4
    float* skip0 = (float*)alloc(736000u * 4);               // [80,50,184]
    float* skip1 = (float*)alloc(368000u * 4);               // [160,25,92]
    float* skip2 = (float*)alloc(191360u * 4);               // [320,13,46]
    float* skip3 = (float*)alloc(103040u * 4);               // [640,7,23]
    float* d4    = (float*)alloc(10304u * 4);                // [64,7,23]
    float* cat3  = (float*)alloc(229632u * 4);               // [384,13,46]
    float* d3    = (float*)alloc(76544u);                    // [32,13,46] 19136*4
    float* cat2  = (float*)alloc(441600u * 4);               // [192,25,92]
    float* d2    = (float*)alloc(147200u);                   // [16,25,92] 36800*4
    float* cat1  = (float*)alloc(883200u * 4);               // [96,50,184]
    float* d1    = (float*)alloc(294400u);                   // [8,50,184] 73600*4

    const int BS = 256;

    // Encoder layer 1 (fused conv+scan)
    k_l1_fused<<<CDIV(36800, BS), BS, 0, stream>>>(x, w1, b1, spk1, skip0);

    // Layer 2: conv over all t, then scan
    {
        int total = 1000 * 8 * 25 * 92;  // 18,400,000
        k_conv_s2<<<CDIV(total, BS), BS, 0, stream>>>(spk1, w2, b2, cbuf,
                                                      4, 50, 184, 8, 25, 92,
                                                      0, 0, total);
        k_scan<<<CDIV(18400, BS), BS, 0, stream>>>(cbuf, spk2, skip1, 8, 2300, 1);
    }
    // Layer 3
    {
        int total = 1000 * 16 * 13 * 46; // 9,568,000
        k_conv_s2<<<CDIV(total, BS), BS, 0, stream>>>(spk2, w3, b3, cbuf,
                                                      8, 25, 92, 16, 13, 46,
                                                      1, 0, total);
        k_scan<<<CDIV(9568, BS), BS, 0, stream>>>(cbuf, spk3, skip2, 16, 598, 1);
    }
    // Layer 4 (no spike output needed)
    {
        int total = 1000 * 32 * 7 * 23;  // 5,152,000
        k_conv_s2<<<CDIV(total, BS), BS, 0, stream>>>(spk3, w4, b4, cbuf,
                                                      16, 13, 46, 32, 7, 23,
                                                      1, 0, total);
        k_scan<<<CDIV(5152, BS), BS, 0, stream>>>(cbuf, spk1 /*dummy*/, skip3,
                                                  32, 161, 0);
    }

    // Decoder
    k_conv3x3_relu<<<CDIV(64 * 7 * 23, BS), BS, 0, stream>>>(skip3, 640, 7, 23,
                                                             dw4, db4, d4, 64);
    k_up_cat<<<CDIV(384 * 13 * 46, BS), BS, 0, stream>>>(d4, 64, 7, 23,
                                                         skip2, 320, cat3, 13, 46);
    k_conv3x3_relu<<<CDIV(32 * 13 * 46, BS), BS, 0, stream>>>(cat3, 384, 13, 46,
                                                              dw3, db3, d3, 32);
    k_up_cat<<<CDIV(192 * 25 * 92, BS), BS, 0, stream>>>(d3, 32, 13, 46,
                                                         skip1, 160, cat2, 25, 92);
    k_conv3x3_relu<<<CDIV(16 * 25 * 92, BS), BS, 0, stream>>>(cat2, 192, 25, 92,
                                                              dw2, db2, d2, 16);
    k_up_cat<<<CDIV(96 * 50 * 184, BS), BS, 0, stream>>>(d2, 16, 25, 92,
                                                         skip0, 80, cat1, 50, 184);
    k_conv3x3_relu<<<CDIV(8 * 50 * 184, BS), BS, 0, stream>>>(cat1, 96, 50, 184,
                                                              dw1, db1, d1, 8);
    k_final<<<CDIV(36800, BS), BS, 0, stream>>>(d1, wo, bo, out);
}

// Round 2
// 2710.759 us; speedup vs baseline: 1.8873x; 1.8873x over previous
//
#include <hip/hip_runtime.h>

#define KBINS  10
#define SBIN   100
#define BETA   0.9f
#define THR    1.0f
#define CDIV(a,b) (((a)+(b)-1)/(b))

// ---------------------------------------------------------------------------
// Layer-1 conv for one 100-step bin: thread per (t,h,w), computes 4 couts.
// x chunk: [100,1,100,368] fp32 -> c1 chunk [100,4,9200] fp32.
// SAME stride-2, pad_lo=(0,0): taps r=2h..2h+2, c=2w..2w+2, OOB masked to 0.
// ---------------------------------------------------------------------------
__global__ void k_conv1(const float* __restrict__ x,
                        const float* __restrict__ w1,
                        const float* __restrict__ b1,
                        float* __restrict__ c1) {
    int n = blockIdx.x * blockDim.x + threadIdx.x;
    if (n >= SBIN * 9200) return;
    int w   = n % 184;
    int tmp = n / 184;
    int h   = tmp % 50;
    int t   = tmp / 50;

    const float* xt = x + (size_t)t * 36800;
    float tap[9];
    #pragma unroll
    for (int kh = 0; kh < 3; kh++) {
        int r = 2 * h + kh;
        bool rok = (r < 100);
        int rc = rok ? r : 99;
        #pragma unroll
        for (int kw = 0; kw < 3; kw++) {
            int cc = 2 * w + kw;
            bool cok = (cc < 368);
            int ccc = cok ? cc : 367;
            float v = xt[rc * 368 + ccc];
            tap[kh * 3 + kw] = (rok && cok) ? v : 0.0f;
        }
    }
    float* ot = c1 + (size_t)t * 36800 + h * 184 + w;
    #pragma unroll
    for (int c = 0; c < 4; c++) {
        float acc = b1[c];
        #pragma unroll
        for (int j = 0; j < 9; j++)
            acc = fmaf(tap[j], w1[c * 9 + j], acc);
        ot[c * 9200] = acc;
    }
}

// ---------------------------------------------------------------------------
// Layer-1 membrane scan for one bin. Thread per (c,hw) pixel. Membrane carry
// lives in mstate (persistent across bins; k==0 resets to 0).
// Reads c1 chunk (L2/L3-hot), writes spk chunk (u8) + skip0 mean/std for bin k.
// ---------------------------------------------------------------------------
__global__ void k_scan1(const float* __restrict__ c1,
                        float* __restrict__ mstate,
                        unsigned char* __restrict__ spk,   // pre-offset to bin
                        float* __restrict__ skip0, int k) {
    int p = blockIdx.x * blockDim.x + threadIdx.x;
    if (p >= 36800) return;
    int c  = p / 9200;
    int hw = p - c * 9200;

    float m = (k == 0) ? 0.0f : mstate[p];
    float s = 0.0f, q = 0.0f;
    #pragma unroll 10
    for (int i = 0; i < SBIN; i++) {
        float v = c1[(size_t)i * 36800 + p];
        m = BETA * m + v;
        float sp = (m - THR > 0.0f) ? 1.0f : 0.0f;
        m -= sp * THR;
        spk[(size_t)i * 36800 + p] = (unsigned char)sp;
        s += m;
        q = fmaf(m, m, q);
    }
    mstate[p] = m;
    float mean = s * (1.0f / SBIN);
    float var  = q * (1.0f / SBIN) - mean * mean;
    float sd   = sqrtf(fmaxf(var, 1e-8f));
    skip0[(size_t)(k * 8 + c) * 9200 + hw]     = mean;
    skip0[(size_t)(k * 8 + 4 + c) * 9200 + hw] = sd;
}

// ---------------------------------------------------------------------------
// Stride-2 conv over all timesteps, u8 spikes in, ALL couts per thread
// (taps loaded once, reused across COUT). Thread per (t,h,w).
// ---------------------------------------------------------------------------
template<int CIN, int COUT, int HIN, int WIN, int HOUT, int WOUT, int PADH, int PADW>
__global__ void k_conv_s2_multi(const unsigned char* __restrict__ spk_in,
                                const float* __restrict__ wt,
                                const float* __restrict__ bias,
                                float* __restrict__ out) {
    const int total = 1000 * HOUT * WOUT;
    int n = blockIdx.x * blockDim.x + threadIdx.x;
    if (n >= total) return;
    int w   = n % WOUT;
    int tmp = n / WOUT;
    int h   = tmp % HOUT;
    int t   = tmp / HOUT;

    int off[9]; float msk[9];
    #pragma unroll
    for (int kh = 0; kh < 3; kh++) {
        int r = 2 * h + kh - PADH;
        bool rok = (r >= 0) && (r < HIN);
        int rc = rok ? r : 0;
        #pragma unroll
        for (int kw = 0; kw < 3; kw++) {
            int cc = 2 * w + kw - PADW;
            bool cok = (cc >= 0) && (cc < WIN);
            int ccc = cok ? cc : 0;
            off[kh * 3 + kw] = rc * WIN + ccc;
            msk[kh * 3 + kw] = (rok && cok) ? 1.0f : 0.0f;
        }
    }

    float acc[COUT];
    #pragma unroll
    for (int co = 0; co < COUT; co++) acc[co] = bias[co];

    const unsigned char* in_t = spk_in + (size_t)t * (CIN * HIN * WIN);
    for (int ci = 0; ci < CIN; ci++) {
        const unsigned char* ic = in_t + ci * HIN * WIN;
        float tap[9];
        #pragma unroll
        for (int j = 0; j < 9; j++)
            tap[j] = msk[j] * (float)ic[off[j]];
        const float* wci = wt + ci * 9;
        #pragma unroll
        for (int co = 0; co < COUT; co++) {
            #pragma unroll
            for (int j = 0; j < 9; j++)
                acc[co] = fmaf(tap[j], wci[(size_t)co * CIN * 9 + j], acc[co]);
        }
    }
    float* ot = out + (size_t)t * (COUT * HOUT * WOUT) + h * WOUT + w;
    #pragma unroll
    for (int co = 0; co < COUT; co++) ot[co * HOUT * WOUT] = acc[co];
}

// ---------------------------------------------------------------------------
// Membrane scan layers 2-4, full 1000 steps. Thread per pixel, coalesced
// cbuf reads, unrolled for load pipelining.
// ---------------------------------------------------------------------------
__global__ void k_scan(const float* __restrict__ cbuf,
                       unsigned char* __restrict__ spk_out,
                       float* __restrict__ skip,
                       int C, int HW, int write_spk) {
    int CHW = C * HW;
    int p = blockIdx.x * blockDim.x + threadIdx.x;
    if (p >= CHW) return;
    int c  = p / HW;
    int hw = p - c * HW;

    float m = 0.0f;
    for (int k = 0; k < KBINS; k++) {
        float s = 0.0f, q = 0.0f;
        #pragma unroll 10
        for (int i = 0; i < SBIN; i++) {
            int t = k * SBIN + i;
            float v = cbuf[(size_t)t * CHW + p];
            m = BETA * m + v;
            float sp = (m - THR > 0.0f) ? 1.0f : 0.0f;
            m -= sp * THR;
            if (write_spk) spk_out[(size_t)t * CHW + p] = (unsigned char)sp;
            s += m;
            q = fmaf(m, m, q);
        }
        float mean = s * (1.0f / SBIN);
        float var  = q * (1.0f / SBIN) - mean * mean;
        float sd   = sqrtf(fmaxf(var, 1e-8f));
        skip[(size_t)(k * 2 * C + c) * HW + hw]     = mean;
        skip[(size_t)(k * 2 * C + C + c) * HW + hw] = sd;
    }
}

// ---------------------------------------------------------------------------
// Decoder: 3x3 stride-1 SAME conv + ReLU.
// ---------------------------------------------------------------------------
__global__ void k_conv3x3_relu(const float* __restrict__ in, int Cin, int H, int W,
                               const float* __restrict__ wt,
                               const float* __restrict__ bias,
                               float* __restrict__ out, int Cout) {
    int total = Cout * H * W;
    int n = blockIdx.x * blockDim.x + threadIdx.x;
    if (n >= total) return;
    int w   = n % W;
    int tmp = n / W;
    int h   = tmp % H;
    int co  = tmp / H;

    float acc = bias[co];
    const float* wco = wt + (size_t)co * Cin * 9;
    for (int ci = 0; ci < Cin; ci++) {
        const float* ic  = in + (size_t)ci * H * W;
        const float* wci = wco + ci * 9;
        #pragma unroll
        for (int kh = 0; kh < 3; kh++) {
            int r = h + kh - 1;
            if ((unsigned)r >= (unsigned)H) continue;
            #pragma unroll
            for (int kw = 0; kw < 3; kw++) {
                int cc = w + kw - 1;
                if ((unsigned)cc >= (unsigned)W) continue;
                acc = fmaf(ic[r * W + cc], wci[kh * 3 + kw], acc);
            }
        }
    }
    out[n] = fmaxf(acc, 0.0f);
}

// ---------------------------------------------------------------------------
// Bilinear upsample (JAX half-pixel, edge-clamp) + channel concat.
// ---------------------------------------------------------------------------
__global__ void k_up_cat(const float* __restrict__ up_src, int Cup, int Hi, int Wi,
                         const float* __restrict__ skip, int Cskip,
                         float* __restrict__ out, int Ho, int Wo) {
    int total = (Cup + Cskip) * Ho * Wo;
    int n = blockIdx.x * blockDim.x + threadIdx.x;
    if (n >= total) return;
    int w   = n % Wo;
    int tmp = n / Wo;
    int h   = tmp % Ho;
    int c   = tmp / Ho;
    float v;
    if (c < Cup) {
        float ph = (h + 0.5f) * (float)Hi / (float)Ho - 0.5f;
        float pw = (w + 0.5f) * (float)Wi / (float)Wo - 0.5f;
        float fh = floorf(ph), fw = floorf(pw);
        int h0 = (int)fh, w0 = (int)fw;
        float ah = ph - fh, aw = pw - fw;
        int h0c = min(max(h0, 0), Hi - 1), h1c = min(max(h0 + 1, 0), Hi - 1);
        int w0c = min(max(w0, 0), Wi - 1), w1c = min(max(w0 + 1, 0), Wi - 1);
        const float* sc = up_src + (size_t)c * Hi * Wi;
        float v00 = sc[h0c * Wi + w0c], v01 = sc[h0c * Wi + w1c];
        float v10 = sc[h1c * Wi + w0c], v11 = sc[h1c * Wi + w1c];
        v = (1.0f - ah) * ((1.0f - aw) * v00 + aw * v01)
          + ah * ((1.0f - aw) * v10 + aw * v11);
    } else {
        v = skip[(size_t)(c - Cup) * Ho * Wo + h * Wo + w];
    }
    out[n] = v;
}

// ---------------------------------------------------------------------------
// Final: bilinear up d1 [8,50,184] -> (100,368), fused 1x1 conv.
// ---------------------------------------------------------------------------
__global__ void k_final(const float* __restrict__ d1,
                        const float* __restrict__ wo,
                        const float* __restrict__ bo,
                        float* __restrict__ out) {
    int n = blockIdx.x * blockDim.x + threadIdx.x;
    if (n >= 36800) return;
    int w = n % 368, h = n / 368;
    float ph = (h + 0.5f) * 0.5f - 0.5f;
    float pw = (w + 0.5f) * 0.5f - 0.5f;
    float fh = floorf(ph), fw = floorf(pw);
    int h0 = (int)fh, w0 = (int)fw;
    float ah = ph - fh, aw = pw - fw;
    int h0c = min(max(h0, 0), 49),  h1c = min(max(h0 + 1, 0), 49);
    int w0c = min(max(w0, 0), 183), w1c = min(max(w0 + 1, 0), 183);
    float acc = bo[0];
    #pragma unroll
    for (int c = 0; c < 8; c++) {
        const float* sc = d1 + c * 9200;
        float v00 = sc[h0c * 184 + w0c], v01 = sc[h0c * 184 + w1c];
        float v10 = sc[h1c * 184 + w0c], v11 = sc[h1c * 184 + w1c];
        float v = (1.0f - ah) * ((1.0f - aw) * v00 + aw * v01)
                + ah * ((1.0f - aw) * v10 + aw * v11);
        acc = fmaf(wo[c], v, acc);
    }
    out[n] = acc;
}

// ---------------------------------------------------------------------------
extern "C" void kernel_launch(void* const* d_in, const int* in_sizes, int n_in,
                              void* d_out, int out_size, void* d_ws, size_t ws_size,
                              hipStream_t stream) {
    (void)in_sizes; (void)n_in; (void)out_size; (void)ws_size;
    const float* x   = (const float*)d_in[0];
    const float* w1  = (const float*)d_in[1];
    const float* b1  = (const float*)d_in[2];
    const float* w2  = (const float*)d_in[3];
    const float* b2  = (const float*)d_in[4];
    const float* w3  = (const float*)d_in[5];
    const float* b3  = (const float*)d_in[6];
    const float* w4  = (const float*)d_in[7];
    const float* b4  = (const float*)d_in[8];
    const float* dw4 = (const float*)d_in[9];
    const float* db4 = (const float*)d_in[10];
    const float* dw3 = (const float*)d_in[11];
    const float* db3 = (const float*)d_in[12];
    const float* dw2 = (const float*)d_in[13];
    const float* db2 = (const float*)d_in[14];
    const float* dw1 = (const float*)d_in[15];
    const float* db1 = (const float*)d_in[16];
    const float* wo  = (const float*)d_in[17];
    const float* bo  = (const float*)d_in[18];
    float* out = (float*)d_out;

    // ---- workspace plan (~131 MB, aliased) ----
    char* ws = (char*)d_ws;
    size_t off = 0;
    auto alloc = [&](size_t bytes) -> void* {
        void* p = ws + off;
        off += (bytes + 255) & ~(size_t)255;
        return p;
    };
    float*         c1      = (float*)alloc(14720000);        // [100,4,9200] bin chunk
    float*         mstate1 = (float*)alloc(147200);          // [36800]
    unsigned char* spk1    = (unsigned char*)alloc(36800000);// [1000,4,9200]
    float*         cbuf    = (float*)alloc(73600000);        // c2/c3/c4 reuse
    float*         skip0   = (float*)alloc(2944000);         // [80,9200]
    float*         skip1   = (float*)alloc(1472000);         // [160,2300]
    float*         skip2   = (float*)alloc(765440);          // [320,598]
    float*         skip3   = (float*)alloc(412160);          // [640,161]
    // spk2/spk3 alias spk1 (spk1 dead after conv2 completes; stream-ordered)
    unsigned char* spk2 = spk1;                              // [1000,8,2300] 18.4MB
    unsigned char* spk3 = spk1 + 18400000;                   // [1000,16,598] 9.57MB
    // decoder buffers alias the c1-chunk region (dead after encoder)
    char* dec = (char*)c1;
    size_t doff = 0;
    auto dalloc = [&](size_t bytes) -> void* {
        void* p = dec + doff;
        doff += (bytes + 255) & ~(size_t)255;
        return p;
    };
    float* d4   = (float*)dalloc(10304u * 4);
    float* cat3 = (float*)dalloc(229632u * 4);
    float* d3   = (float*)dalloc(19136u * 4);
    float* cat2 = (float*)dalloc(441600u * 4);
    float* d2   = (float*)dalloc(36800u * 4);
    float* cat1 = (float*)dalloc(883200u * 4);
    float* d1   = (float*)dalloc(73600u * 4);

    const int BS = 256;

    // ---- encoder layer 1: per-bin conv + scan (chunk stays cache-hot) ----
    for (int k = 0; k < KBINS; k++) {
        k_conv1<<<CDIV(SBIN * 9200, BS), BS, 0, stream>>>(
            x + (size_t)k * SBIN * 36800, w1, b1, c1);
        k_scan1<<<CDIV(36800, BS), BS, 0, stream>>>(
            c1, mstate1, spk1 + (size_t)k * SBIN * 36800, skip0, k);
    }

    // ---- layers 2-4: full-t conv (all couts/thread) + scan ----
    k_conv_s2_multi<4, 8, 50, 184, 25, 92, 0, 0>
        <<<CDIV(1000 * 25 * 92, BS), BS, 0, stream>>>(spk1, w2, b2, cbuf);
    k_scan<<<CDIV(18400, BS), BS, 0, stream>>>(cbuf, spk2, skip1, 8, 2300, 1);

    k_conv_s2_multi<8, 16, 25, 92, 13, 46, 1, 0>
        <<<CDIV(1000 * 13 * 46, BS), BS, 0, stream>>>(spk2, w3, b3, cbuf);
    k_scan<<<CDIV(9568, BS), BS, 0, stream>>>(cbuf, spk3, skip2, 16, 598, 1);

    k_conv_s2_multi<16, 32, 13, 46, 7, 23, 1, 0>
        <<<CDIV(1000 * 7 * 23, BS), BS, 0, stream>>>(spk3, w4, b4, cbuf);
    k_scan<<<CDIV(5152, BS), BS, 0, stream>>>(cbuf, (unsigned char*)c1 /*dummy*/,
                                              skip3, 32, 161, 0);

    // ---- decoder ----
    k_conv3x3_relu<<<CDIV(64 * 161, BS), BS, 0, stream>>>(skip3, 640, 7, 23,
                                                          dw4, db4, d4, 64);
    k_up_cat<<<CDIV(384 * 598, BS), BS, 0, stream>>>(d4, 64, 7, 23,
                                                     skip2, 320, cat3, 13, 46);
    k_conv3x3_relu<<<CDIV(32 * 598, BS), BS, 0, stream>>>(cat3, 384, 13, 46,
                                                          dw3, db3, d3, 32);
    k_up_cat<<<CDIV(192 * 2300, BS), BS, 0, stream>>>(d3, 32, 13, 46,
                                                      skip1, 160, cat2, 25, 92);
    k_conv3x3_relu<<<CDIV(16 * 2300, BS), BS, 0, stream>>>(cat2, 192, 25, 92,
                                                           dw2, db2, d2, 16);
    k_up_cat<<<CDIV(96 * 9200, BS), BS, 0, stream>>>(d2, 16, 25, 92,
                                                     skip0, 80, cat1, 50, 184);
    k_conv3x3_relu<<<CDIV(8 * 9200, BS), BS, 0, stream>>>(cat1, 96, 50, 184,
                                                          dw1, db1, d1, 8);
    k_final<<<CDIV(36800, BS), BS, 0, stream>>>(d1, wo, bo, out);
}

// Round 3
// 1635.449 us; speedup vs baseline: 3.1282x; 1.6575x over previous
//
#include <hip/hip_runtime.h>

#define KBINS  10
#define SBIN   100
#define BETA   0.9f
#define THR    1.0f
#define CDIV(a,b) (((a)+(b)-1)/(b))

// ---------------------------------------------------------------------------
// Layer-1 conv for one 100-step bin: thread per (t,h,w), computes 4 couts.
// x chunk: [100,1,100,368] fp32 -> c1 chunk [100,4,9200] fp32.
// SAME stride-2, pad_lo=(0,0): taps r=2h..2h+2, c=2w..2w+2, OOB masked to 0.
// ---------------------------------------------------------------------------
__global__ void k_conv1(const float* __restrict__ x,
                        const float* __restrict__ w1,
                        const float* __restrict__ b1,
                        float* __restrict__ c1) {
    int n = blockIdx.x * blockDim.x + threadIdx.x;
    if (n >= SBIN * 9200) return;
    int w   = n % 184;
    int tmp = n / 184;
    int h   = tmp % 50;
    int t   = tmp / 50;

    const float* xt = x + (size_t)t * 36800;
    float tap[9];
    #pragma unroll
    for (int kh = 0; kh < 3; kh++) {
        int r = 2 * h + kh;
        bool rok = (r < 100);
        int rc = rok ? r : 99;
        #pragma unroll
        for (int kw = 0; kw < 3; kw++) {
            int cc = 2 * w + kw;
            bool cok = (cc < 368);
            int ccc = cok ? cc : 367;
            float v = xt[rc * 368 + ccc];
            tap[kh * 3 + kw] = (rok && cok) ? v : 0.0f;
        }
    }
    float* ot = c1 + (size_t)t * 36800 + h * 184 + w;
    #pragma unroll
    for (int c = 0; c < 4; c++) {
        float acc = b1[c];
        #pragma unroll
        for (int j = 0; j < 9; j++)
            acc = fmaf(tap[j], w1[c * 9 + j], acc);
        ot[c * 9200] = acc;
    }
}

// ---------------------------------------------------------------------------
// Layer-1 membrane scan for one bin. Thread per (c,hw) pixel.
// ---------------------------------------------------------------------------
__global__ void k_scan1(const float* __restrict__ c1,
                        float* __restrict__ mstate,
                        unsigned char* __restrict__ spk,   // pre-offset to bin
                        float* __restrict__ skip0, int k) {
    int p = blockIdx.x * blockDim.x + threadIdx.x;
    if (p >= 36800) return;
    int c  = p / 9200;
    int hw = p - c * 9200;

    float m = (k == 0) ? 0.0f : mstate[p];
    float s = 0.0f, q = 0.0f;
    #pragma unroll 10
    for (int i = 0; i < SBIN; i++) {
        float v = c1[(size_t)i * 36800 + p];
        m = BETA * m + v;
        float sp = (m - THR > 0.0f) ? 1.0f : 0.0f;
        m -= sp * THR;
        spk[(size_t)i * 36800 + p] = (unsigned char)sp;
        s += m;
        q = fmaf(m, m, q);
    }
    mstate[p] = m;
    float mean = s * (1.0f / SBIN);
    float var  = q * (1.0f / SBIN) - mean * mean;
    float sd   = sqrtf(fmaxf(var, 1e-8f));
    skip0[(size_t)(k * 8 + c) * 9200 + hw]     = mean;
    skip0[(size_t)(k * 8 + 4 + c) * 9200 + hw] = sd;
}

// ---------------------------------------------------------------------------
// Stride-2 conv over all timesteps, u8 spikes in, ALL couts per thread.
// ---------------------------------------------------------------------------
template<int CIN, int COUT, int HIN, int WIN, int HOUT, int WOUT, int PADH, int PADW>
__global__ void k_conv_s2_multi(const unsigned char* __restrict__ spk_in,
                                const float* __restrict__ wt,
                                const float* __restrict__ bias,
                                float* __restrict__ out) {
    const int total = 1000 * HOUT * WOUT;
    int n = blockIdx.x * blockDim.x + threadIdx.x;
    if (n >= total) return;
    int w   = n % WOUT;
    int tmp = n / WOUT;
    int h   = tmp % HOUT;
    int t   = tmp / HOUT;

    int off[9]; float msk[9];
    #pragma unroll
    for (int kh = 0; kh < 3; kh++) {
        int r = 2 * h + kh - PADH;
        bool rok = (r >= 0) && (r < HIN);
        int rc = rok ? r : 0;
        #pragma unroll
        for (int kw = 0; kw < 3; kw++) {
            int cc = 2 * w + kw - PADW;
            bool cok = (cc >= 0) && (cc < WIN);
            int ccc = cok ? cc : 0;
            off[kh * 3 + kw] = rc * WIN + ccc;
            msk[kh * 3 + kw] = (rok && cok) ? 1.0f : 0.0f;
        }
    }

    float acc[COUT];
    #pragma unroll
    for (int co = 0; co < COUT; co++) acc[co] = bias[co];

    const unsigned char* in_t = spk_in + (size_t)t * (CIN * HIN * WIN);
    for (int ci = 0; ci < CIN; ci++) {
        const unsigned char* ic = in_t + ci * HIN * WIN;
        float tap[9];
        #pragma unroll
        for (int j = 0; j < 9; j++)
            tap[j] = msk[j] * (float)ic[off[j]];
        const float* wci = wt + ci * 9;
        #pragma unroll
        for (int co = 0; co < COUT; co++) {
            #pragma unroll
            for (int j = 0; j < 9; j++)
                acc[co] = fmaf(tap[j], wci[(size_t)co * CIN * 9 + j], acc[co]);
        }
    }
    float* ot = out + (size_t)t * (COUT * HOUT * WOUT) + h * WOUT + w;
    #pragma unroll
    for (int co = 0; co < COUT; co++) ot[co * HOUT * WOUT] = acc[co];
}

// ---------------------------------------------------------------------------
// Membrane scan layers 2-4, full 1000 steps.
// ---------------------------------------------------------------------------
__global__ void k_scan(const float* __restrict__ cbuf,
                       unsigned char* __restrict__ spk_out,
                       float* __restrict__ skip,
                       int C, int HW, int write_spk) {
    int CHW = C * HW;
    int p = blockIdx.x * blockDim.x + threadIdx.x;
    if (p >= CHW) return;
    int c  = p / HW;
    int hw = p - c * HW;

    float m = 0.0f;
    for (int k = 0; k < KBINS; k++) {
        float s = 0.0f, q = 0.0f;
        #pragma unroll 10
        for (int i = 0; i < SBIN; i++) {
            int t = k * SBIN + i;
            float v = cbuf[(size_t)t * CHW + p];
            m = BETA * m + v;
            float sp = (m - THR > 0.0f) ? 1.0f : 0.0f;
            m -= sp * THR;
            if (write_spk) spk_out[(size_t)t * CHW + p] = (unsigned char)sp;
            s += m;
            q = fmaf(m, m, q);
        }
        float mean = s * (1.0f / SBIN);
        float var  = q * (1.0f / SBIN) - mean * mean;
        float sd   = sqrtf(fmaxf(var, 1e-8f));
        skip[(size_t)(k * 2 * C + c) * HW + hw]     = mean;
        skip[(size_t)(k * 2 * C + C + c) * HW + hw] = sd;
    }
}

// ---------------------------------------------------------------------------
// Decoder conv, split-K partials: grid = (HW tiles, Cout, chunks).
// Each thread: partial dot over CS input channels for one (co, pixel).
// Weights wave-uniform (co,chunk from blockIdx); taps branch-free masked.
// part layout: [chunk][co][HW]
// ---------------------------------------------------------------------------
__global__ void k_conv_part(const float* __restrict__ in, int Cin, int H, int W,
                            const float* __restrict__ wt,
                            float* __restrict__ part,
                            int Cout, int CS) {
    int HW  = H * W;
    int pix = blockIdx.x * blockDim.x + threadIdx.x;
    if (pix >= HW) return;
    int co    = blockIdx.y;
    int chunk = blockIdx.z;
    int h = pix / W, w = pix - h * W;

    int off[9]; float msk[9];
    #pragma unroll
    for (int kh = 0; kh < 3; kh++) {
        int r = h + kh - 1;
        bool rok = (r >= 0) && (r < H);
        int rc = rok ? r : 0;
        #pragma unroll
        for (int kw = 0; kw < 3; kw++) {
            int cc = w + kw - 1;
            bool cok = (cc >= 0) && (cc < W);
            int ccc = cok ? cc : 0;
            off[kh * 3 + kw] = rc * W + ccc;
            msk[kh * 3 + kw] = (rok && cok) ? 1.0f : 0.0f;
        }
    }

    const float* ibase = in + (size_t)chunk * CS * HW;
    const float* wbase = wt + ((size_t)co * Cin + (size_t)chunk * CS) * 9;
    float acc = 0.0f;
    #pragma unroll 2
    for (int ci = 0; ci < CS; ci++) {
        const float* ic = ibase + (size_t)ci * HW;
        const float* wc = wbase + ci * 9;
        #pragma unroll
        for (int j = 0; j < 9; j++)
            acc = fmaf(msk[j] * ic[off[j]], wc[j], acc);
    }
    part[((size_t)chunk * Cout + co) * HW + pix] = acc;
}

// Sum partials + bias + ReLU -> d buffer.
__global__ void k_reduce_relu(const float* __restrict__ part,
                              const float* __restrict__ bias,
                              float* __restrict__ out,
                              int Cout, int HW, int nchunks) {
    int n = blockIdx.x * blockDim.x + threadIdx.x;
    if (n >= Cout * HW) return;
    int co = n / HW;
    float acc = bias[co];
    for (int c = 0; c < nchunks; c++)
        acc += part[(size_t)c * Cout * HW + n];
    out[n] = fmaxf(acc, 0.0f);
}

// ---------------------------------------------------------------------------
// Bilinear upsample (JAX half-pixel, edge-clamp) + channel concat.
// ---------------------------------------------------------------------------
__global__ void k_up_cat(const float* __restrict__ up_src, int Cup, int Hi, int Wi,
                         const float* __restrict__ skip, int Cskip,
                         float* __restrict__ out, int Ho, int Wo) {
    int total = (Cup + Cskip) * Ho * Wo;
    int n = blockIdx.x * blockDim.x + threadIdx.x;
    if (n >= total) return;
    int w   = n % Wo;
    int tmp = n / Wo;
    int h   = tmp % Ho;
    int c   = tmp / Ho;
    float v;
    if (c < Cup) {
        float ph = (h + 0.5f) * (float)Hi / (float)Ho - 0.5f;
        float pw = (w + 0.5f) * (float)Wi / (float)Wo - 0.5f;
        float fh = floorf(ph), fw = floorf(pw);
        int h0 = (int)fh, w0 = (int)fw;
        float ah = ph - fh, aw = pw - fw;
        int h0c = min(max(h0, 0), Hi - 1), h1c = min(max(h0 + 1, 0), Hi - 1);
        int w0c = min(max(w0, 0), Wi - 1), w1c = min(max(w0 + 1, 0), Wi - 1);
        const float* sc = up_src + (size_t)c * Hi * Wi;
        float v00 = sc[h0c * Wi + w0c], v01 = sc[h0c * Wi + w1c];
        float v10 = sc[h1c * Wi + w0c], v11 = sc[h1c * Wi + w1c];
        v = (1.0f - ah) * ((1.0f - aw) * v00 + aw * v01)
          + ah * ((1.0f - aw) * v10 + aw * v11);
    } else {
        v = skip[(size_t)(c - Cup) * Ho * Wo + h * Wo + w];
    }
    out[n] = v;
}

// ---------------------------------------------------------------------------
// Final: bilinear up d1 [8,50,184] -> (100,368), fused 1x1 conv.
// ---------------------------------------------------------------------------
__global__ void k_final(const float* __restrict__ d1,
                        const float* __restrict__ wo,
                        const float* __restrict__ bo,
                        float* __restrict__ out) {
    int n = blockIdx.x * blockDim.x + threadIdx.x;
    if (n >= 36800) return;
    int w = n % 368, h = n / 368;
    float ph = (h + 0.5f) * 0.5f - 0.5f;
    float pw = (w + 0.5f) * 0.5f - 0.5f;
    float fh = floorf(ph), fw = floorf(pw);
    int h0 = (int)fh, w0 = (int)fw;
    float ah = ph - fh, aw = pw - fw;
    int h0c = min(max(h0, 0), 49),  h1c = min(max(h0 + 1, 0), 49);
    int w0c = min(max(w0, 0), 183), w1c = min(max(w0 + 1, 0), 183);
    float acc = bo[0];
    #pragma unroll
    for (int c = 0; c < 8; c++) {
        const float* sc = d1 + c * 9200;
        float v00 = sc[h0c * 184 + w0c], v01 = sc[h0c * 184 + w1c];
        float v10 = sc[h1c * 184 + w0c], v11 = sc[h1c * 184 + w1c];
        float v = (1.0f - ah) * ((1.0f - aw) * v00 + aw * v01)
                + ah * ((1.0f - aw) * v10 + aw * v11);
        acc = fmaf(wo[c], v, acc);
    }
    out[n] = acc;
}

// ---------------------------------------------------------------------------
extern "C" void kernel_launch(void* const* d_in, const int* in_sizes, int n_in,
                              void* d_out, int out_size, void* d_ws, size_t ws_size,
                              hipStream_t stream) {
    (void)in_sizes; (void)n_in; (void)out_size; (void)ws_size;
    const float* x   = (const float*)d_in[0];
    const float* w1  = (const float*)d_in[1];
    const float* b1  = (const float*)d_in[2];
    const float* w2  = (const float*)d_in[3];
    const float* b2  = (const float*)d_in[4];
    const float* w3  = (const float*)d_in[5];
    const float* b3  = (const float*)d_in[6];
    const float* w4  = (const float*)d_in[7];
    const float* b4  = (const float*)d_in[8];
    const float* dw4 = (const float*)d_in[9];
    const float* db4 = (const float*)d_in[10];
    const float* dw3 = (const float*)d_in[11];
    const float* db3 = (const float*)d_in[12];
    const float* dw2 = (const float*)d_in[13];
    const float* db2 = (const float*)d_in[14];
    const float* dw1 = (const float*)d_in[15];
    const float* db1 = (const float*)d_in[16];
    const float* wo  = (const float*)d_in[17];
    const float* bo  = (const float*)d_in[18];
    float* out = (float*)d_out;

    // ---- workspace plan (~131 MB, aliased) ----
    char* ws = (char*)d_ws;
    size_t off = 0;
    auto alloc = [&](size_t bytes) -> void* {
        void* p = ws + off;
        off += (bytes + 255) & ~(size_t)255;
        return p;
    };
    float*         c1      = (float*)alloc(14720000);        // [100,4,9200] bin chunk
    float*         mstate1 = (float*)alloc(147200);          // [36800]
    unsigned char* spk1    = (unsigned char*)alloc(36800000);// [1000,4,9200]
    float*         cbuf    = (float*)alloc(73600000);        // c2/c3/c4 reuse
    float*         skip0   = (float*)alloc(2944000);         // [80,9200]
    float*         skip1   = (float*)alloc(1472000);         // [160,2300]
    float*         skip2   = (float*)alloc(765440);          // [320,598]
    float*         skip3   = (float*)alloc(412160);          // [640,161]
    unsigned char* spk2 = spk1;                              // alias, [1000,8,2300]
    unsigned char* spk3 = spk1 + 18400000;                   // alias, [1000,16,598]
    // decoder buffers alias the c1-chunk region (dead after encoder)
    char* dec = (char*)c1;
    size_t doff = 0;
    auto dalloc = [&](size_t bytes) -> void* {
        void* p = dec + doff;
        doff += (bytes + 255) & ~(size_t)255;
        return p;
    };
    float* d4   = (float*)dalloc(10304u * 4);
    float* cat3 = (float*)dalloc(229632u * 4);
    float* d3   = (float*)dalloc(19136u * 4);
    float* cat2 = (float*)dalloc(441600u * 4);
    float* d2   = (float*)dalloc(36800u * 4);
    float* cat1 = (float*)dalloc(883200u * 4);
    float* d1   = (float*)dalloc(73600u * 4);
    float* part = (float*)dalloc(1048576u);                  // split-K partials

    const int BS = 256;

    // ---- encoder layer 1: per-bin conv + scan (chunk stays cache-hot) ----
    for (int k = 0; k < KBINS; k++) {
        k_conv1<<<CDIV(SBIN * 9200, BS), BS, 0, stream>>>(
            x + (size_t)k * SBIN * 36800, w1, b1, c1);
        k_scan1<<<CDIV(36800, BS), BS, 0, stream>>>(
            c1, mstate1, spk1 + (size_t)k * SBIN * 36800, skip0, k);
    }

    // ---- layers 2-4: full-t conv (all couts/thread) + scan ----
    k_conv_s2_multi<4, 8, 50, 184, 25, 92, 0, 0>
        <<<CDIV(1000 * 25 * 92, BS), BS, 0, stream>>>(spk1, w2, b2, cbuf);
    k_scan<<<CDIV(18400, BS), BS, 0, stream>>>(cbuf, spk2, skip1, 8, 2300, 1);

    k_conv_s2_multi<8, 16, 25, 92, 13, 46, 1, 0>
        <<<CDIV(1000 * 13 * 46, BS), BS, 0, stream>>>(spk2, w3, b3, cbuf);
    k_scan<<<CDIV(9568, BS), BS, 0, stream>>>(cbuf, spk3, skip2, 16, 598, 1);

    k_conv_s2_multi<16, 32, 13, 46, 7, 23, 1, 0>
        <<<CDIV(1000 * 7 * 23, BS), BS, 0, stream>>>(spk3, w4, b4, cbuf);
    k_scan<<<CDIV(5152, BS), BS, 0, stream>>>(cbuf, (unsigned char*)cat1 /*dummy*/,
                                              skip3, 32, 161, 0);

    // ---- decoder: split-K conv partials + reduce, then up+cat ----
    // L4: skip3[640,7,23] -> d4[64,7,23], CS=64, 10 chunks
    {
        dim3 g(CDIV(161, BS), 64, 10);
        k_conv_part<<<g, BS, 0, stream>>>(skip3, 640, 7, 23, dw4, part, 64, 64);
        k_reduce_relu<<<CDIV(64 * 161, BS), BS, 0, stream>>>(part, db4, d4, 64, 161, 10);
    }
    k_up_cat<<<CDIV(384 * 598, BS), BS, 0, stream>>>(d4, 64, 7, 23,
                                                     skip2, 320, cat3, 13, 46);
    // L3: cat3[384,13,46] -> d3[32,13,46], CS=48, 8 chunks
    {
        dim3 g(CDIV(598, BS), 32, 8);
        k_conv_part<<<g, BS, 0, stream>>>(cat3, 384, 13, 46, dw3, part, 32, 48);
        k_reduce_relu<<<CDIV(32 * 598, BS), BS, 0, stream>>>(part, db3, d3, 32, 598, 8);
    }
    k_up_cat<<<CDIV(192 * 2300, BS), BS, 0, stream>>>(d3, 32, 13, 46,
                                                      skip1, 160, cat2, 25, 92);
    // L2: cat2[192,25,92] -> d2[16,25,92], CS=48, 4 chunks
    {
        dim3 g(CDIV(2300, BS), 16, 4);
        k_conv_part<<<g, BS, 0, stream>>>(cat2, 192, 25, 92, dw2, part, 16, 48);
        k_reduce_relu<<<CDIV(16 * 2300, BS), BS, 0, stream>>>(part, db2, d2, 16, 2300, 4);
    }
    k_up_cat<<<CDIV(96 * 9200, BS), BS, 0, stream>>>(d2, 16, 25, 92,
                                                     skip0, 80, cat1, 50, 184);
    // L1: cat1[96,50,184] -> d1[8,50,184], CS=48, 2 chunks
    {
        dim3 g(CDIV(9200, BS), 8, 2);
        k_conv_part<<<g, BS, 0, stream>>>(cat1, 96, 50, 184, dw1, part, 8, 48);
        k_reduce_relu<<<CDIV(8 * 9200, BS), BS, 0, stream>>>(part, db1, d1, 8, 9200, 2);
    }
    k_final<<<CDIV(36800, BS), BS, 0, stream>>>(d1, wo, bo, out);
}

// Round 4
// 985.744 us; speedup vs baseline: 5.1900x; 1.6591x over previous
//
#include <hip/hip_runtime.h>

#define KBINS  10
#define SBIN   100
#define BETA   0.9f
#define THR    1.0f
#define CDIV(a,b) (((a)+(b)-1)/(b))

// ---------------------------------------------------------------------------
// Layer-1 conv for one 100-step bin: thread per (t,h,w), computes 4 couts.
// ---------------------------------------------------------------------------
__global__ void k_conv1(const float* __restrict__ x,
                        const float* __restrict__ w1,
                        const float* __restrict__ b1,
                        float* __restrict__ c1) {
    int n = blockIdx.x * blockDim.x + threadIdx.x;
    if (n >= SBIN * 9200) return;
    int w   = n % 184;
    int tmp = n / 184;
    int h   = tmp % 50;
    int t   = tmp / 50;

    const float* xt = x + (size_t)t * 36800;
    float tap[9];
    #pragma unroll
    for (int kh = 0; kh < 3; kh++) {
        int r = 2 * h + kh;
        bool rok = (r < 100);
        int rc = rok ? r : 99;
        #pragma unroll
        for (int kw = 0; kw < 3; kw++) {
            int cc = 2 * w + kw;
            bool cok = (cc < 368);
            int ccc = cok ? cc : 367;
            float v = xt[rc * 368 + ccc];
            tap[kh * 3 + kw] = (rok && cok) ? v : 0.0f;
        }
    }
    float* ot = c1 + (size_t)t * 36800 + h * 184 + w;
    #pragma unroll
    for (int c = 0; c < 4; c++) {
        float acc = b1[c];
        #pragma unroll
        for (int j = 0; j < 9; j++)
            acc = fmaf(tap[j], w1[c * 9 + j], acc);
        ot[c * 9200] = acc;
    }
}

// ---------------------------------------------------------------------------
// Layer-1 membrane scan for one bin: double-buffered register prefetch.
// ---------------------------------------------------------------------------
__global__ void k_scan1(const float* __restrict__ c1,
                        float* __restrict__ mstate,
                        unsigned char* __restrict__ spk,   // pre-offset to bin
                        float* __restrict__ skip0, int k) {
    const int PF = 10;
    int p = blockIdx.x * blockDim.x + threadIdx.x;
    if (p >= 36800) return;
    int c  = p / 9200;
    int hw = p - c * 9200;

    float m = (k == 0) ? 0.0f : mstate[p];
    float va[PF], vb[PF];
    #pragma unroll
    for (int j = 0; j < PF; j++) va[j] = c1[(size_t)j * 36800 + p];

    float s = 0.0f, q = 0.0f;
    for (int b = 0; b < SBIN / PF; b++) {
        int t0 = b * PF, tn = t0 + PF;
        bool more = (tn < SBIN);
        #pragma unroll
        for (int j = 0; j < PF; j++)
            vb[j] = more ? c1[(size_t)(tn + j) * 36800 + p] : 0.0f;
        #pragma unroll
        for (int j = 0; j < PF; j++) {
            m = fmaf(m, BETA, va[j]);
            float sp = (m - THR > 0.0f) ? 1.0f : 0.0f;
            m -= sp * THR;
            spk[(size_t)(t0 + j) * 36800 + p] = (unsigned char)sp;
            s += m;
            q = fmaf(m, m, q);
        }
        #pragma unroll
        for (int j = 0; j < PF; j++) va[j] = vb[j];
    }
    mstate[p] = m;
    float mean = s * (1.0f / SBIN);
    float var  = q * (1.0f / SBIN) - mean * mean;
    float sd   = sqrtf(fmaxf(var, 1e-8f));
    skip0[(size_t)(k * 8 + c) * 9200 + hw]     = mean;
    skip0[(size_t)(k * 8 + 4 + c) * 9200 + hw] = sd;
}

// ---------------------------------------------------------------------------
// Stride-2 conv over all timesteps, u8 spikes in, ALL couts per thread.
// ---------------------------------------------------------------------------
template<int CIN, int COUT, int HIN, int WIN, int HOUT, int WOUT, int PADH, int PADW>
__global__ void k_conv_s2_multi(const unsigned char* __restrict__ spk_in,
                                const float* __restrict__ wt,
                                const float* __restrict__ bias,
                                float* __restrict__ out) {
    const int total = 1000 * HOUT * WOUT;
    int n = blockIdx.x * blockDim.x + threadIdx.x;
    if (n >= total) return;
    int w   = n % WOUT;
    int tmp = n / WOUT;
    int h   = tmp % HOUT;
    int t   = tmp / HOUT;

    int off[9]; float msk[9];
    #pragma unroll
    for (int kh = 0; kh < 3; kh++) {
        int r = 2 * h + kh - PADH;
        bool rok = (r >= 0) && (r < HIN);
        int rc = rok ? r : 0;
        #pragma unroll
        for (int kw = 0; kw < 3; kw++) {
            int cc = 2 * w + kw - PADW;
            bool cok = (cc >= 0) && (cc < WIN);
            int ccc = cok ? cc : 0;
            off[kh * 3 + kw] = rc * WIN + ccc;
            msk[kh * 3 + kw] = (rok && cok) ? 1.0f : 0.0f;
        }
    }

    float acc[COUT];
    #pragma unroll
    for (int co = 0; co < COUT; co++) acc[co] = bias[co];

    const unsigned char* in_t = spk_in + (size_t)t * (CIN * HIN * WIN);
    for (int ci = 0; ci < CIN; ci++) {
        const unsigned char* ic = in_t + ci * HIN * WIN;
        float tap[9];
        #pragma unroll
        for (int j = 0; j < 9; j++)
            tap[j] = msk[j] * (float)ic[off[j]];
        const float* wci = wt + ci * 9;
        #pragma unroll
        for (int co = 0; co < COUT; co++) {
            #pragma unroll
            for (int j = 0; j < 9; j++)
                acc[co] = fmaf(tap[j], wci[(size_t)co * CIN * 9 + j], acc[co]);
        }
    }
    float* ot = out + (size_t)t * (COUT * HOUT * WOUT) + h * WOUT + w;
    #pragma unroll
    for (int co = 0; co < COUT; co++) ot[co * HOUT * WOUT] = acc[co];
}

// ---------------------------------------------------------------------------
// Membrane scan layers 2-4, full 1000 steps, double-buffered prefetch.
// ---------------------------------------------------------------------------
__global__ void k_scan(const float* __restrict__ cbuf,
                       unsigned char* __restrict__ spk_out,
                       float* __restrict__ skip,
                       int C, int HW, int write_spk) {
    const int PF = 10;
    int CHW = C * HW;
    int p = blockIdx.x * blockDim.x + threadIdx.x;
    if (p >= CHW) return;
    int c  = p / HW;
    int hw = p - c * HW;

    float m = 0.0f;
    float va[PF], vb[PF];
    #pragma unroll
    for (int j = 0; j < PF; j++) va[j] = cbuf[(size_t)j * CHW + p];

    for (int k = 0; k < KBINS; k++) {
        float s = 0.0f, q = 0.0f;
        for (int b = 0; b < SBIN / PF; b++) {
            int t0 = k * SBIN + b * PF;
            int tn = t0 + PF;
            bool more = (tn < KBINS * SBIN);
            #pragma unroll
            for (int j = 0; j < PF; j++)
                vb[j] = more ? cbuf[(size_t)(tn + j) * CHW + p] : 0.0f;
            #pragma unroll
            for (int j = 0; j < PF; j++) {
                m = fmaf(m, BETA, va[j]);
                float sp = (m - THR > 0.0f) ? 1.0f : 0.0f;
                m -= sp * THR;
                if (write_spk) spk_out[(size_t)(t0 + j) * CHW + p] = (unsigned char)sp;
                s += m;
                q = fmaf(m, m, q);
            }
            #pragma unroll
            for (int j = 0; j < PF; j++) va[j] = vb[j];
        }
        float mean = s * (1.0f / SBIN);
        float var  = q * (1.0f / SBIN) - mean * mean;
        float sd   = sqrtf(fmaxf(var, 1e-8f));
        skip[(size_t)(k * 2 * C + c) * HW + hw]     = mean;
        skip[(size_t)(k * 2 * C + C + c) * HW + hw] = sd;
    }
}

// ---------------------------------------------------------------------------
// Decoder conv, split-K partials: grid = (HW tiles, Cout, chunks).
// ---------------------------------------------------------------------------
__global__ void k_conv_part(const float* __restrict__ in, int Cin, int H, int W,
                            const float* __restrict__ wt,
                            float* __restrict__ part,
                            int Cout, int CS) {
    int HW  = H * W;
    int pix = blockIdx.x * blockDim.x + threadIdx.x;
    if (pix >= HW) return;
    int co    = blockIdx.y;
    int chunk = blockIdx.z;
    int h = pix / W, w = pix - h * W;

    int off[9]; float msk[9];
    #pragma unroll
    for (int kh = 0; kh < 3; kh++) {
        int r = h + kh - 1;
        bool rok = (r >= 0) && (r < H);
        int rc = rok ? r : 0;
        #pragma unroll
        for (int kw = 0; kw < 3; kw++) {
            int cc = w + kw - 1;
            bool cok = (cc >= 0) && (cc < W);
            int ccc = cok ? cc : 0;
            off[kh * 3 + kw] = rc * W + ccc;
            msk[kh * 3 + kw] = (rok && cok) ? 1.0f : 0.0f;
        }
    }

    const float* ibase = in + (size_t)chunk * CS * HW;
    const float* wbase = wt + ((size_t)co * Cin + (size_t)chunk * CS) * 9;
    float acc = 0.0f;
    #pragma unroll 2
    for (int ci = 0; ci < CS; ci++) {
        const float* ic = ibase + (size_t)ci * HW;
        const float* wc = wbase + ci * 9;
        #pragma unroll
        for (int j = 0; j < 9; j++)
            acc = fmaf(msk[j] * ic[off[j]], wc[j], acc);
    }
    part[((size_t)chunk * Cout + co) * HW + pix] = acc;
}

// Sum partials + bias + ReLU -> d buffer.
__global__ void k_reduce_relu(const float* __restrict__ part,
                              const float* __restrict__ bias,
                              float* __restrict__ out,
                              int Cout, int HW, int nchunks) {
    int n = blockIdx.x * blockDim.x + threadIdx.x;
    if (n >= Cout * HW) return;
    int co = n / HW;
    float acc = bias[co];
    for (int c = 0; c < nchunks; c++)
        acc += part[(size_t)c * Cout * HW + n];
    out[n] = fmaxf(acc, 0.0f);
}

// ---------------------------------------------------------------------------
// Bilinear upsample (JAX half-pixel, edge-clamp) + channel concat.
// ---------------------------------------------------------------------------
__global__ void k_up_cat(const float* __restrict__ up_src, int Cup, int Hi, int Wi,
                         const float* __restrict__ skip, int Cskip,
                         float* __restrict__ out, int Ho, int Wo) {
    int total = (Cup + Cskip) * Ho * Wo;
    int n = blockIdx.x * blockDim.x + threadIdx.x;
    if (n >= total) return;
    int w   = n % Wo;
    int tmp = n / Wo;
    int h   = tmp % Ho;
    int c   = tmp / Ho;
    float v;
    if (c < Cup) {
        float ph = (h + 0.5f) * (float)Hi / (float)Ho - 0.5f;
        float pw = (w + 0.5f) * (float)Wi / (float)Wo - 0.5f;
        float fh = floorf(ph), fw = floorf(pw);
        int h0 = (int)fh, w0 = (int)fw;
        float ah = ph - fh, aw = pw - fw;
        int h0c = min(max(h0, 0), Hi - 1), h1c = min(max(h0 + 1, 0), Hi - 1);
        int w0c = min(max(w0, 0), Wi - 1), w1c = min(max(w0 + 1, 0), Wi - 1);
        const float* sc = up_src + (size_t)c * Hi * Wi;
        float v00 = sc[h0c * Wi + w0c], v01 = sc[h0c * Wi + w1c];
        float v10 = sc[h1c * Wi + w0c], v11 = sc[h1c * Wi + w1c];
        v = (1.0f - ah) * ((1.0f - aw) * v00 + aw * v01)
          + ah * ((1.0f - aw) * v10 + aw * v11);
    } else {
        v = skip[(size_t)(c - Cup) * Ho * Wo + h * Wo + w];
    }
    out[n] = v;
}

// ---------------------------------------------------------------------------
// Final: bilinear up d1 [8,50,184] -> (100,368), fused 1x1 conv.
// ---------------------------------------------------------------------------
__global__ void k_final(const float* __restrict__ d1,
                        const float* __restrict__ wo,
                        const float* __restrict__ bo,
                        float* __restrict__ out) {
    int n = blockIdx.x * blockDim.x + threadIdx.x;
    if (n >= 36800) return;
    int w = n % 368, h = n / 368;
    float ph = (h + 0.5f) * 0.5f - 0.5f;
    float pw = (w + 0.5f) * 0.5f - 0.5f;
    float fh = floorf(ph), fw = floorf(pw);
    int h0 = (int)fh, w0 = (int)fw;
    float ah = ph - fh, aw = pw - fw;
    int h0c = min(max(h0, 0), 49),  h1c = min(max(h0 + 1, 0), 49);
    int w0c = min(max(w0, 0), 183), w1c = min(max(w0 + 1, 0), 183);
    float acc = bo[0];
    #pragma unroll
    for (int c = 0; c < 8; c++) {
        const float* sc = d1 + c * 9200;
        float v00 = sc[h0c * 184 + w0c], v01 = sc[h0c * 184 + w1c];
        float v10 = sc[h1c * 184 + w0c], v11 = sc[h1c * 184 + w1c];
        float v = (1.0f - ah) * ((1.0f - aw) * v00 + aw * v01)
                + ah * ((1.0f - aw) * v10 + aw * v11);
        acc = fmaf(wo[c], v, acc);
    }
    out[n] = acc;
}

// ---------------------------------------------------------------------------
extern "C" void kernel_launch(void* const* d_in, const int* in_sizes, int n_in,
                              void* d_out, int out_size, void* d_ws, size_t ws_size,
                              hipStream_t stream) {
    (void)in_sizes; (void)n_in; (void)out_size; (void)ws_size;
    const float* x   = (const float*)d_in[0];
    const float* w1  = (const float*)d_in[1];
    const float* b1  = (const float*)d_in[2];
    const float* w2  = (const float*)d_in[3];
    const float* b2  = (const float*)d_in[4];
    const float* w3  = (const float*)d_in[5];
    const float* b3  = (const float*)d_in[6];
    const float* w4  = (const float*)d_in[7];
    const float* b4  = (const float*)d_in[8];
    const float* dw4 = (const float*)d_in[9];
    const float* db4 = (const float*)d_in[10];
    const float* dw3 = (const float*)d_in[11];
    const float* db3 = (const float*)d_in[12];
    const float* dw2 = (const float*)d_in[13];
    const float* db2 = (const float*)d_in[14];
    const float* dw1 = (const float*)d_in[15];
    const float* db1 = (const float*)d_in[16];
    const float* wo  = (const float*)d_in[17];
    const float* bo  = (const float*)d_in[18];
    float* out = (float*)d_out;

    // ---- workspace plan (~131 MB, aliased) ----
    char* ws = (char*)d_ws;
    size_t off = 0;
    auto alloc = [&](size_t bytes) -> void* {
        void* p = ws + off;
        off += (bytes + 255) & ~(size_t)255;
        return p;
    };
    float*         c1      = (float*)alloc(14720000);        // [100,4,9200] bin chunk
    float*         mstate1 = (float*)alloc(147200);          // [36800]
    unsigned char* spk1    = (unsigned char*)alloc(36800000);// [1000,4,9200]
    float*         cbuf    = (float*)alloc(73600000);        // c2/c3/c4 reuse
    float*         skip0   = (float*)alloc(2944000);         // [80,9200]
    float*         skip1   = (float*)alloc(1472000);         // [160,2300]
    float*         skip2   = (float*)alloc(765440);          // [320,598]
    float*         skip3   = (float*)alloc(412160);          // [640,161]
    unsigned char* spk2 = spk1;                              // alias, [1000,8,2300]
    unsigned char* spk3 = spk1 + 18400000;                   // alias, [1000,16,598]
    // decoder buffers alias the c1-chunk region (dead after encoder)
    char* dec = (char*)c1;
    size_t doff = 0;
    auto dalloc = [&](size_t bytes) -> void* {
        void* p = dec + doff;
        doff += (bytes + 255) & ~(size_t)255;
        return p;
    };
    float* d4   = (float*)dalloc(10304u * 4);
    float* cat3 = (float*)dalloc(229632u * 4);
    float* d3   = (float*)dalloc(19136u * 4);
    float* cat2 = (float*)dalloc(441600u * 4);
    float* d2   = (float*)dalloc(36800u * 4);
    float* cat1 = (float*)dalloc(883200u * 4);
    float* d1   = (float*)dalloc(73600u * 4);
    float* part = (float*)dalloc(1048576u);                  // split-K partials

    const int BS = 256;
    const int SBS = 64;   // scan block size: spread across CUs

    // ---- encoder layer 1: per-bin conv + scan (chunk stays cache-hot) ----
    for (int k = 0; k < KBINS; k++) {
        k_conv1<<<CDIV(SBIN * 9200, BS), BS, 0, stream>>>(
            x + (size_t)k * SBIN * 36800, w1, b1, c1);
        k_scan1<<<CDIV(36800, SBS), SBS, 0, stream>>>(
            c1, mstate1, spk1 + (size_t)k * SBIN * 36800, skip0, k);
    }

    // ---- layers 2-4: full-t conv (all couts/thread) + scan ----
    k_conv_s2_multi<4, 8, 50, 184, 25, 92, 0, 0>
        <<<CDIV(1000 * 25 * 92, BS), BS, 0, stream>>>(spk1, w2, b2, cbuf);
    k_scan<<<CDIV(18400, SBS), SBS, 0, stream>>>(cbuf, spk2, skip1, 8, 2300, 1);

    k_conv_s2_multi<8, 16, 25, 92, 13, 46, 1, 0>
        <<<CDIV(1000 * 13 * 46, BS), BS, 0, stream>>>(spk2, w3, b3, cbuf);
    k_scan<<<CDIV(9568, SBS), SBS, 0, stream>>>(cbuf, spk3, skip2, 16, 598, 1);

    k_conv_s2_multi<16, 32, 13, 46, 7, 23, 1, 0>
        <<<CDIV(1000 * 7 * 23, BS), BS, 0, stream>>>(spk3, w4, b4, cbuf);
    k_scan<<<CDIV(5152, SBS), SBS, 0, stream>>>(cbuf, (unsigned char*)cat1 /*dummy*/,
                                                skip3, 32, 161, 0);

    // ---- decoder: split-K conv partials + reduce, then up+cat ----
    {
        dim3 g(CDIV(161, BS), 64, 10);
        k_conv_part<<<g, BS, 0, stream>>>(skip3, 640, 7, 23, dw4, part, 64, 64);
        k_reduce_relu<<<CDIV(64 * 161, BS), BS, 0, stream>>>(part, db4, d4, 64, 161, 10);
    }
    k_up_cat<<<CDIV(384 * 598, BS), BS, 0, stream>>>(d4, 64, 7, 23,
                                                     skip2, 320, cat3, 13, 46);
    {
        dim3 g(CDIV(598, BS), 32, 8);
        k_conv_part<<<g, BS, 0, stream>>>(cat3, 384, 13, 46, dw3, part, 32, 48);
        k_reduce_relu<<<CDIV(32 * 598, BS), BS, 0, stream>>>(part, db3, d3, 32, 598, 8);
    }
    k_up_cat<<<CDIV(192 * 2300, BS), BS, 0, stream>>>(d3, 32, 13, 46,
                                                      skip1, 160, cat2, 25, 92);
    {
        dim3 g(CDIV(2300, BS), 16, 4);
        k_conv_part<<<g, BS, 0, stream>>>(cat2, 192, 25, 92, dw2, part, 16, 48);
        k_reduce_relu<<<CDIV(16 * 2300, BS), BS, 0, stream>>>(part, db2, d2, 16, 2300, 4);
    }
    k_up_cat<<<CDIV(96 * 9200, BS), BS, 0, stream>>>(d2, 16, 25, 92,
                                                     skip0, 80, cat1, 50, 184);
    {
        dim3 g(CDIV(9200, BS), 8, 2);
        k_conv_part<<<g, BS, 0, stream>>>(cat1, 96, 50, 184, dw1, part, 8, 48);
        k_reduce_relu<<<CDIV(8 * 9200, BS), BS, 0, stream>>>(part, db1, d1, 8, 9200, 2);
    }
    k_final<<<CDIV(36800, BS), BS, 0, stream>>>(d1, wo, bo, out);
}